// Round 1
// baseline (590.293 us; speedup 1.0000x reference)
//
#include <hip/hip_runtime.h>
#include <math.h>

// ---------------------------------------------------------------------------
// GNN link predictor: 2-layer GraphSAGE (mean agg) + dot-product + sigmoid.
// Key restructuring: transform-then-aggregate (linearity of mean), CSR-by-dst
// built per call (no float atomics), wave-per-node aggregation (lane=channel).
// ---------------------------------------------------------------------------

#define HID 64

// ---------------- CSR build ----------------

__global__ __launch_bounds__(256)
void k_hist(const int* __restrict__ edst, int* __restrict__ deg, int E) {
    int e = blockIdx.x * 256 + threadIdx.x;
    if (e < E) atomicAdd(&deg[edst[e]], 1);
}

// block scans 1024 elements (256 thr x 4), writes per-block exclusive scan + block sum
__global__ __launch_bounds__(256)
void k_scan1(const int* __restrict__ deg, int* __restrict__ offs,
             int* __restrict__ bsums, int n) {
    __shared__ int lds[256];
    int t = threadIdx.x;
    int base = blockIdx.x * 1024 + t * 4;
    int v0 = 0, v1 = 0, v2 = 0, v3 = 0;
    if (base + 0 < n) v0 = deg[base + 0];
    if (base + 1 < n) v1 = deg[base + 1];
    if (base + 2 < n) v2 = deg[base + 2];
    if (base + 3 < n) v3 = deg[base + 3];
    int ts = v0 + v1 + v2 + v3;
    lds[t] = ts;
    __syncthreads();
    for (int off = 1; off < 256; off <<= 1) {
        int x = (t >= off) ? lds[t - off] : 0;
        __syncthreads();
        lds[t] += x;
        __syncthreads();
    }
    int excl = lds[t] - ts;  // exclusive prefix of thread sums within block
    if (base + 0 < n) offs[base + 0] = excl;
    if (base + 1 < n) offs[base + 1] = excl + v0;
    if (base + 2 < n) offs[base + 2] = excl + v0 + v1;
    if (base + 3 < n) offs[base + 3] = excl + v0 + v1 + v2;
    if (t == 255) bsums[blockIdx.x] = lds[255];
}

// single-block exclusive scan of block sums (nb <= 256)
__global__ __launch_bounds__(256)
void k_scan2(int* __restrict__ bsums, int nb) {
    __shared__ int lds[256];
    int t = threadIdx.x;
    int v = (t < nb) ? bsums[t] : 0;
    lds[t] = v;
    __syncthreads();
    for (int off = 1; off < 256; off <<= 1) {
        int x = (t >= off) ? lds[t - off] : 0;
        __syncthreads();
        lds[t] += x;
        __syncthreads();
    }
    if (t < nb) bsums[t] = lds[t] - v;  // exclusive
}

// add back block offsets; copy to pos (scatter cursor)
__global__ __launch_bounds__(256)
void k_scan3(int* __restrict__ offs, const int* __restrict__ bsums,
             int* __restrict__ pos, int n) {
    int i = blockIdx.x * 256 + threadIdx.x;
    if (i < n) {
        int o = offs[i] + bsums[i >> 10];
        offs[i] = o;
        pos[i] = o;
    }
}

__global__ __launch_bounds__(256)
void k_scatter(const int* __restrict__ esrc, const int* __restrict__ edst,
               int* __restrict__ pos, int* __restrict__ sorted, int E) {
    int e = blockIdx.x * 256 + threadIdx.x;
    if (e < E) {
        int d = edst[e];
        int slot = atomicAdd(&pos[d], 1);
        sorted[slot] = esrc[e];
    }
}

// ---------------- dual GEMM: P = X@Wl^T, Q = X@Wr^T (both 64 x K) ----------------
// block = 256 threads, 64 rows/block; thread computes 4 rows x 8 out-cols.
// W (both matrices) staged transposed in LDS: sWT[k][c], c in [0,128).
// X streamed from global (each row fetched once per block, L1-broadcast).

__device__ __forceinline__ float f4get(const float4& v, int k) {
    return k == 0 ? v.x : k == 1 ? v.y : k == 2 ? v.z : v.w;
}

template <int K>
__global__ __launch_bounds__(256)
void gemm_dual(const float* __restrict__ X, const float* __restrict__ Wl,
               const float* __restrict__ Wr, float* __restrict__ P,
               float* __restrict__ Qo, int N) {
    __shared__ float sWT[K][128];  // K=128 -> 64 KB exactly
    const int t = threadIdx.x;
    for (int i = t; i < 128 * K; i += 256) {
        const int c = i / K;        // K is power of 2 -> shift
        const int k = i & (K - 1);
        sWT[k][c] = (c < 64) ? Wl[c * K + k] : Wr[(c - 64) * K + k];
    }
    __syncthreads();

    const int og = t & 15;   // out-col group: cols [og*8, og*8+8)
    const int rg = t >> 4;   // row group: 16 groups x 4 rows = 64 rows
    const int rbase = blockIdx.x * 64 + rg * 4;

    const float* xrow[4];
    bool ok[4];
#pragma unroll
    for (int i = 0; i < 4; ++i) {
        int r = rbase + i;
        ok[i] = (r < N);
        xrow[i] = X + (size_t)(ok[i] ? r : 0) * K;
    }

    float acc[4][8];
#pragma unroll
    for (int i = 0; i < 4; ++i)
#pragma unroll
        for (int j = 0; j < 8; ++j) acc[i][j] = 0.f;

    for (int k0 = 0; k0 < K; k0 += 4) {
        float4 xr[4];
#pragma unroll
        for (int i = 0; i < 4; ++i) xr[i] = *(const float4*)(xrow[i] + k0);
#pragma unroll
        for (int kk = 0; kk < 4; ++kk) {
            float4 w0 = *(const float4*)&sWT[k0 + kk][og * 8];
            float4 w1 = *(const float4*)&sWT[k0 + kk][og * 8 + 4];
#pragma unroll
            for (int i = 0; i < 4; ++i) {
                float xs = f4get(xr[i], kk);
                acc[i][0] = fmaf(xs, w0.x, acc[i][0]);
                acc[i][1] = fmaf(xs, w0.y, acc[i][1]);
                acc[i][2] = fmaf(xs, w0.z, acc[i][2]);
                acc[i][3] = fmaf(xs, w0.w, acc[i][3]);
                acc[i][4] = fmaf(xs, w1.x, acc[i][4]);
                acc[i][5] = fmaf(xs, w1.y, acc[i][5]);
                acc[i][6] = fmaf(xs, w1.z, acc[i][6]);
                acc[i][7] = fmaf(xs, w1.w, acc[i][7]);
            }
        }
    }

    float* dst = (og < 8) ? P : Qo;
    const int cb = (og < 8) ? og * 8 : og * 8 - 64;
#pragma unroll
    for (int i = 0; i < 4; ++i) {
        if (ok[i]) {
            float* p = dst + (size_t)(rbase + i) * HID + cb;
            *(float4*)p = make_float4(acc[i][0], acc[i][1], acc[i][2], acc[i][3]);
            *(float4*)(p + 4) = make_float4(acc[i][4], acc[i][5], acc[i][6], acc[i][7]);
        }
    }
}

// ---------------- aggregation: H = relu(mean_{s in N(n)} P[s] + bias + Qin[n]) ----
// one 64-lane wave per node, lane = channel. Qin/H may alias (in-place).

__global__ __launch_bounds__(256)
void k_agg(const float* __restrict__ P, const float* Qin,
           const float* __restrict__ bias, const int* __restrict__ offs,
           const int* __restrict__ deg, const int* __restrict__ sorted,
           float* H, int N) {
    int wid = blockIdx.x * 4 + (threadIdx.x >> 6);
    int lane = threadIdx.x & 63;
    if (wid >= N) return;
    int off = __builtin_amdgcn_readfirstlane(offs[wid]);
    int c = __builtin_amdgcn_readfirstlane(deg[wid]);
    float acc = 0.f;
    int i = 0;
    for (; i + 3 < c; i += 4) {
        int s0 = sorted[off + i];
        int s1 = sorted[off + i + 1];
        int s2 = sorted[off + i + 2];
        int s3 = sorted[off + i + 3];
        float a0 = P[(size_t)s0 * HID + lane];
        float a1 = P[(size_t)s1 * HID + lane];
        float a2 = P[(size_t)s2 * HID + lane];
        float a3 = P[(size_t)s3 * HID + lane];
        acc += (a0 + a1) + (a2 + a3);
    }
    for (; i < c; ++i) acc += P[(size_t)sorted[off + i] * HID + lane];
    float inv = 1.0f / (float)(c > 0 ? c : 1);
    float v = acc * inv + bias[lane] + Qin[(size_t)wid * HID + lane];
    H[(size_t)wid * HID + lane] = v > 0.f ? v : 0.f;
}

// ---------------- query: out[q] = sigmoid(sum_c Z[s][c]*Z[d][c]) ----------------

__global__ __launch_bounds__(256)
void k_query(const float* __restrict__ Z, const int* __restrict__ src,
             const int* __restrict__ dst, float* __restrict__ out, int Q) {
    int q = blockIdx.x * 4 + (threadIdx.x >> 6);
    int lane = threadIdx.x & 63;
    if (q >= Q) return;
    int s = __builtin_amdgcn_readfirstlane(src[q]);
    int d = __builtin_amdgcn_readfirstlane(dst[q]);
    float v = Z[(size_t)s * HID + lane] * Z[(size_t)d * HID + lane];
#pragma unroll
    for (int m = 32; m > 0; m >>= 1) v += __shfl_xor(v, m, 64);
    if (lane == 0) out[q] = 1.0f / (1.0f + __expf(-v));
}

// ---------------- launch ----------------

extern "C" void kernel_launch(void* const* d_in, const int* in_sizes, int n_in,
                              void* d_out, int out_size, void* d_ws, size_t ws_size,
                              hipStream_t stream) {
    const float* x    = (const float*)d_in[0];
    const int*   ei   = (const int*)d_in[1];
    const int*   qsrc = (const int*)d_in[2];
    const int*   qdst = (const int*)d_in[3];
    const float* Wl1  = (const float*)d_in[4];
    const float* bl1  = (const float*)d_in[5];
    const float* Wr1  = (const float*)d_in[6];
    const float* Wl2  = (const float*)d_in[7];
    const float* bl2  = (const float*)d_in[8];
    const float* Wr2  = (const float*)d_in[9];
    float* out = (float*)d_out;

    const int N = in_sizes[0] / 128;  // IN_CH = 128
    const int E = in_sizes[1] / 2;
    const int Q = in_sizes[2];

    const int* esrc = ei;
    const int* edst = ei + E;

    // workspace layout (floats/ints)
    float* A = (float*)d_ws;              // N x 64 : p1, then p2
    float* B = A + (size_t)N * HID;       // N x 64 : q1, then h (in place)
    float* C = B + (size_t)N * HID;       // N x 64 : q2, then z (in place)
    int* deg    = (int*)(C + (size_t)N * HID);
    int* offs   = deg + N;
    int* pos    = offs + N;
    int* bsums  = pos + N;                // up to 256 block sums
    int* sorted = bsums + 256;            // E ints

    const int gE = (E + 255) / 256;
    const int nblk = (N + 1023) / 1024;   // <= 256
    const int gN = (N + 255) / 256;
    const int gG = (N + 63) / 64;
    const int gA = (N + 3) / 4;
    const int gQ = (Q + 3) / 4;

    // CSR build
    hipMemsetAsync(deg, 0, sizeof(int) * (size_t)N, stream);
    k_hist<<<gE, 256, 0, stream>>>(edst, deg, E);
    k_scan1<<<nblk, 256, 0, stream>>>(deg, offs, bsums, N);
    k_scan2<<<1, 256, 0, stream>>>(bsums, nblk);
    k_scan3<<<gN, 256, 0, stream>>>(offs, bsums, pos, N);
    k_scatter<<<gE, 256, 0, stream>>>(esrc, edst, pos, sorted, E);

    // layer 1: p1 = x@Wl1^T (A), q1 = x@Wr1^T (B); h = relu(mean+b+q1) -> B
    gemm_dual<128><<<gG, 256, 0, stream>>>(x, Wl1, Wr1, A, B, N);
    k_agg<<<gA, 256, 0, stream>>>(A, B, bl1, offs, deg, sorted, B, N);

    // layer 2: p2 = h@Wl2^T (A), q2 = h@Wr2^T (C); z = relu(mean+b+q2) -> C
    gemm_dual<64><<<gG, 256, 0, stream>>>(B, Wl2, Wr2, A, C, N);
    k_agg<<<gA, 256, 0, stream>>>(A, C, bl2, offs, deg, sorted, C, N);

    // queries
    k_query<<<gQ, 256, 0, stream>>>(C, qsrc, qdst, out, Q);
}

// Round 2
// 493.921 us; speedup vs baseline: 1.1951x; 1.1951x over previous
//
#include <hip/hip_runtime.h>
#include <math.h>

// ---------------------------------------------------------------------------
// GNN link predictor: 2-layer GraphSAGE (mean agg) + dot-product + sigmoid.
// Restructurings:
//  - transform-then-aggregate (mean is linear) -> aggregate in 64-dim space
//  - CSR-by-dst built per call; scatter is ATOMIC-FREE: edge ranks are the
//    histogram atomic's return value (R2: removed pos-cursor RMW chain,
//    scatter was 126us latency-bound at 11% HBM)
//  - wave-per-node pull aggregation (lane = channel, coalesced 256B rows)
// ---------------------------------------------------------------------------

#define HID 64

// ---------------- CSR build ----------------

// histogram + per-edge rank (return value of the atomic we needed anyway)
__global__ __launch_bounds__(256)
void k_hist(const int* __restrict__ edst, int* __restrict__ deg,
            int* __restrict__ rank, int E) {
    int e = blockIdx.x * 256 + threadIdx.x;
    if (e < E) rank[e] = atomicAdd(&deg[edst[e]], 1);
}

// block scans 1024 elements (256 thr x 4), writes per-block exclusive scan + block sum
__global__ __launch_bounds__(256)
void k_scan1(const int* __restrict__ deg, int* __restrict__ offs,
             int* __restrict__ bsums, int n) {
    __shared__ int lds[256];
    int t = threadIdx.x;
    int base = blockIdx.x * 1024 + t * 4;
    int v0 = 0, v1 = 0, v2 = 0, v3 = 0;
    if (base + 0 < n) v0 = deg[base + 0];
    if (base + 1 < n) v1 = deg[base + 1];
    if (base + 2 < n) v2 = deg[base + 2];
    if (base + 3 < n) v3 = deg[base + 3];
    int ts = v0 + v1 + v2 + v3;
    lds[t] = ts;
    __syncthreads();
    for (int off = 1; off < 256; off <<= 1) {
        int x = (t >= off) ? lds[t - off] : 0;
        __syncthreads();
        lds[t] += x;
        __syncthreads();
    }
    int excl = lds[t] - ts;  // exclusive prefix of thread sums within block
    if (base + 0 < n) offs[base + 0] = excl;
    if (base + 1 < n) offs[base + 1] = excl + v0;
    if (base + 2 < n) offs[base + 2] = excl + v0 + v1;
    if (base + 3 < n) offs[base + 3] = excl + v0 + v1 + v2;
    if (t == 255) bsums[blockIdx.x] = lds[255];
}

// single-block exclusive scan of block sums (nb <= 256)
__global__ __launch_bounds__(256)
void k_scan2(int* __restrict__ bsums, int nb) {
    __shared__ int lds[256];
    int t = threadIdx.x;
    int v = (t < nb) ? bsums[t] : 0;
    lds[t] = v;
    __syncthreads();
    for (int off = 1; off < 256; off <<= 1) {
        int x = (t >= off) ? lds[t - off] : 0;
        __syncthreads();
        lds[t] += x;
        __syncthreads();
    }
    if (t < nb) bsums[t] = lds[t] - v;  // exclusive
}

// add back block offsets
__global__ __launch_bounds__(256)
void k_scan3(int* __restrict__ offs, const int* __restrict__ bsums, int n) {
    int i = blockIdx.x * 256 + threadIdx.x;
    if (i < n) offs[i] += bsums[i >> 10];
}

// atomic-free scatter: slot = offs[dst] + rank (precomputed in k_hist)
__global__ __launch_bounds__(256)
void k_scatter(const int* __restrict__ esrc, const int* __restrict__ edst,
               const int* __restrict__ offs, const int* __restrict__ rank,
               int* __restrict__ sorted, int E) {
    int e = blockIdx.x * 256 + threadIdx.x;
    if (e < E) {
        int d = edst[e];
        sorted[offs[d] + rank[e]] = esrc[e];
    }
}

// ---------------- dual GEMM: P = X@Wl^T, Q = X@Wr^T (both 64 x K) ----------------
// block = 256 threads, 64 rows/block; thread computes 4 rows x 8 out-cols.
// W (both matrices) staged transposed in LDS: sWT[k][c], c in [0,128).
// X streamed from global (each row fetched once per block, L1-broadcast).

__device__ __forceinline__ float f4get(const float4& v, int k) {
    return k == 0 ? v.x : k == 1 ? v.y : k == 2 ? v.z : v.w;
}

template <int K>
__global__ __launch_bounds__(256)
void gemm_dual(const float* __restrict__ X, const float* __restrict__ Wl,
               const float* __restrict__ Wr, float* __restrict__ P,
               float* __restrict__ Qo, int N) {
    __shared__ float sWT[K][128];  // K=128 -> 64 KB exactly
    const int t = threadIdx.x;
    for (int i = t; i < 128 * K; i += 256) {
        const int c = i / K;        // K is power of 2 -> shift
        const int k = i & (K - 1);
        sWT[k][c] = (c < 64) ? Wl[c * K + k] : Wr[(c - 64) * K + k];
    }
    __syncthreads();

    const int og = t & 15;   // out-col group: cols [og*8, og*8+8)
    const int rg = t >> 4;   // row group: 16 groups x 4 rows = 64 rows
    const int rbase = blockIdx.x * 64 + rg * 4;

    const float* xrow[4];
    bool ok[4];
#pragma unroll
    for (int i = 0; i < 4; ++i) {
        int r = rbase + i;
        ok[i] = (r < N);
        xrow[i] = X + (size_t)(ok[i] ? r : 0) * K;
    }

    float acc[4][8];
#pragma unroll
    for (int i = 0; i < 4; ++i)
#pragma unroll
        for (int j = 0; j < 8; ++j) acc[i][j] = 0.f;

    for (int k0 = 0; k0 < K; k0 += 4) {
        float4 xr[4];
#pragma unroll
        for (int i = 0; i < 4; ++i) xr[i] = *(const float4*)(xrow[i] + k0);
#pragma unroll
        for (int kk = 0; kk < 4; ++kk) {
            float4 w0 = *(const float4*)&sWT[k0 + kk][og * 8];
            float4 w1 = *(const float4*)&sWT[k0 + kk][og * 8 + 4];
#pragma unroll
            for (int i = 0; i < 4; ++i) {
                float xs = f4get(xr[i], kk);
                acc[i][0] = fmaf(xs, w0.x, acc[i][0]);
                acc[i][1] = fmaf(xs, w0.y, acc[i][1]);
                acc[i][2] = fmaf(xs, w0.z, acc[i][2]);
                acc[i][3] = fmaf(xs, w0.w, acc[i][3]);
                acc[i][4] = fmaf(xs, w1.x, acc[i][4]);
                acc[i][5] = fmaf(xs, w1.y, acc[i][5]);
                acc[i][6] = fmaf(xs, w1.z, acc[i][6]);
                acc[i][7] = fmaf(xs, w1.w, acc[i][7]);
            }
        }
    }

    float* dst = (og < 8) ? P : Qo;
    const int cb = (og < 8) ? og * 8 : og * 8 - 64;
#pragma unroll
    for (int i = 0; i < 4; ++i) {
        if (ok[i]) {
            float* p = dst + (size_t)(rbase + i) * HID + cb;
            *(float4*)p = make_float4(acc[i][0], acc[i][1], acc[i][2], acc[i][3]);
            *(float4*)(p + 4) = make_float4(acc[i][4], acc[i][5], acc[i][6], acc[i][7]);
        }
    }
}

// ---------------- aggregation: H = relu(mean_{s in N(n)} P[s] + bias + Qin[n]) ----
// one 64-lane wave per node, lane = channel. Qin/H may alias (in-place).

__global__ __launch_bounds__(256)
void k_agg(const float* __restrict__ P, const float* Qin,
           const float* __restrict__ bias, const int* __restrict__ offs,
           const int* __restrict__ deg, const int* __restrict__ sorted,
           float* H, int N) {
    int wid = blockIdx.x * 4 + (threadIdx.x >> 6);
    int lane = threadIdx.x & 63;
    if (wid >= N) return;
    int off = __builtin_amdgcn_readfirstlane(offs[wid]);
    int c = __builtin_amdgcn_readfirstlane(deg[wid]);
    float acc = 0.f;
    int i = 0;
    for (; i + 3 < c; i += 4) {
        int s0 = sorted[off + i];
        int s1 = sorted[off + i + 1];
        int s2 = sorted[off + i + 2];
        int s3 = sorted[off + i + 3];
        float a0 = P[(size_t)s0 * HID + lane];
        float a1 = P[(size_t)s1 * HID + lane];
        float a2 = P[(size_t)s2 * HID + lane];
        float a3 = P[(size_t)s3 * HID + lane];
        acc += (a0 + a1) + (a2 + a3);
    }
    for (; i < c; ++i) acc += P[(size_t)sorted[off + i] * HID + lane];
    float inv = 1.0f / (float)(c > 0 ? c : 1);
    float v = acc * inv + bias[lane] + Qin[(size_t)wid * HID + lane];
    H[(size_t)wid * HID + lane] = v > 0.f ? v : 0.f;
}

// ---------------- query: out[q] = sigmoid(sum_c Z[s][c]*Z[d][c]) ----------------

__global__ __launch_bounds__(256)
void k_query(const float* __restrict__ Z, const int* __restrict__ src,
             const int* __restrict__ dst, float* __restrict__ out, int Q) {
    int q = blockIdx.x * 4 + (threadIdx.x >> 6);
    int lane = threadIdx.x & 63;
    if (q >= Q) return;
    int s = __builtin_amdgcn_readfirstlane(src[q]);
    int d = __builtin_amdgcn_readfirstlane(dst[q]);
    float v = Z[(size_t)s * HID + lane] * Z[(size_t)d * HID + lane];
#pragma unroll
    for (int m = 32; m > 0; m >>= 1) v += __shfl_xor(v, m, 64);
    if (lane == 0) out[q] = 1.0f / (1.0f + __expf(-v));
}

// ---------------- launch ----------------

extern "C" void kernel_launch(void* const* d_in, const int* in_sizes, int n_in,
                              void* d_out, int out_size, void* d_ws, size_t ws_size,
                              hipStream_t stream) {
    const float* x    = (const float*)d_in[0];
    const int*   ei   = (const int*)d_in[1];
    const int*   qsrc = (const int*)d_in[2];
    const int*   qdst = (const int*)d_in[3];
    const float* Wl1  = (const float*)d_in[4];
    const float* bl1  = (const float*)d_in[5];
    const float* Wr1  = (const float*)d_in[6];
    const float* Wl2  = (const float*)d_in[7];
    const float* bl2  = (const float*)d_in[8];
    const float* Wr2  = (const float*)d_in[9];
    float* out = (float*)d_out;

    const int N = in_sizes[0] / 128;  // IN_CH = 128
    const int E = in_sizes[1] / 2;
    const int Q = in_sizes[2];

    const int* esrc = ei;
    const int* edst = ei + E;

    // workspace layout (floats/ints)
    float* A = (float*)d_ws;              // N x 64 : p1, then p2
    float* B = A + (size_t)N * HID;       // N x 64 : q1, then h (in place)
    float* C = B + (size_t)N * HID;       // N x 64 : q2, then z (in place)
    int* deg    = (int*)(C + (size_t)N * HID);
    int* offs   = deg + N;
    int* bsums  = offs + N;               // up to 256 block sums
    int* sorted = bsums + 256;            // E ints
    // rank[] (E ints) aliases A: A is dead until gemm1, rank is dead after scatter
    int* rank   = (int*)A;

    const int gE = (E + 255) / 256;
    const int nblk = (N + 1023) / 1024;   // <= 256
    const int gN = (N + 255) / 256;
    const int gG = (N + 63) / 64;
    const int gA = (N + 3) / 4;
    const int gQ = (Q + 3) / 4;

    // CSR build (scatter is atomic-free: rank captured during histogram)
    hipMemsetAsync(deg, 0, sizeof(int) * (size_t)N, stream);
    k_hist<<<gE, 256, 0, stream>>>(edst, deg, rank, E);
    k_scan1<<<nblk, 256, 0, stream>>>(deg, offs, bsums, N);
    k_scan2<<<1, 256, 0, stream>>>(bsums, nblk);
    k_scan3<<<gN, 256, 0, stream>>>(offs, bsums, N);
    k_scatter<<<gE, 256, 0, stream>>>(esrc, edst, offs, rank, sorted, E);

    // layer 1: p1 = x@Wl1^T (A), q1 = x@Wr1^T (B); h = relu(mean+b+q1) -> B
    gemm_dual<128><<<gG, 256, 0, stream>>>(x, Wl1, Wr1, A, B, N);
    k_agg<<<gA, 256, 0, stream>>>(A, B, bl1, offs, deg, sorted, B, N);

    // layer 2: p2 = h@Wl2^T (A), q2 = h@Wr2^T (C); z = relu(mean+b+q2) -> C
    gemm_dual<64><<<gG, 256, 0, stream>>>(B, Wl2, Wr2, A, C, N);
    k_agg<<<gA, 256, 0, stream>>>(A, C, bl2, offs, deg, sorted, C, N);

    // queries
    k_query<<<gQ, 256, 0, stream>>>(C, qsrc, qdst, out, Q);
}